// Round 1
// baseline (278.302 us; speedup 1.0000x reference)
//
#include <hip/hip_runtime.h>
#include <math.h>

#define C 512
#define NPIX 4096   // 64*64
#define BATCH 16
#define O 512
#define R 6
#define LN_EPS 1e-5f

// ws layout (floats):
// [0, 3072)      psi[r*C+c]
// [3072, 6144)   wpsi[r*C+c] = ln_w[c]*psi[r,c]
// [6144, 6152)   swp[r] = sum_c ln_w[c]*psi[r,c]   (6 used)
// [6152, 6160)   sbp[r] = sum_c ln_b[c]*psi[r,c]   (6 used)
// [6160, 9232)   M[r*O+o] = sum_c psi[r,c]*fc_w[o,c] + fc_b[o]

__global__ __launch_bounds__(512) void setup_psi(const float* __restrict__ lnw,
                                                 const float* __restrict__ lnb,
                                                 float* __restrict__ ws) {
    __shared__ float sh_psi[R * C];
    const int c = threadIdx.x;  // 512 threads, one per channel
    float t = -1.0f + 2.0f * (float)c / 511.0f;
    float xd = tanhf(t) * 4.31662479035539984911f;  // sqrt(11)+1
    float g = expf(-0.5f * xd * xd);
    const float pi_m14 = 0.75112554446494248286f;   // pi^-0.25
    float rows[R];
    rows[0] = pi_m14 * g;
    rows[1] = 1.41421356237309504880f * pi_m14 * xd * g;
    #pragma unroll
    for (int k = 2; k <= 5; ++k)
        rows[k] = sqrtf(2.0f / k) * xd * rows[k - 1] - sqrtf((k - 1.0f) / k) * rows[k - 2];
    float w = lnw[c];
    #pragma unroll
    for (int r = 0; r < R; ++r) {
        sh_psi[r * C + c] = rows[r];
        ws[r * C + c] = rows[r];
        ws[3072 + r * C + c] = rows[r] * w;
    }
    __syncthreads();
    if (threadIdx.x < 12) {
        int r = (threadIdx.x < 6) ? threadIdx.x : threadIdx.x - 6;
        const float* vec = (threadIdx.x < 6) ? lnw : lnb;
        float sacc = 0.f;
        for (int c2 = 0; c2 < C; ++c2) sacc += vec[c2] * sh_psi[r * C + c2];
        ws[(threadIdx.x < 6 ? 6144 : 6152) + r] = sacc;
    }
}

__global__ __launch_bounds__(64) void setup_M(const float* __restrict__ fcw,
                                              const float* __restrict__ fcb,
                                              float* __restrict__ ws) {
    const int o = blockIdx.x;       // 512 blocks
    const int lane = threadIdx.x;   // 64 threads = 1 wave
    const float* psi = ws;
    float acc[R] = {0.f, 0.f, 0.f, 0.f, 0.f, 0.f};
    for (int c = lane; c < C; c += 64) {
        float w = fcw[o * C + c];
        #pragma unroll
        for (int r = 0; r < R; ++r) acc[r] += psi[r * C + c] * w;
    }
    #pragma unroll
    for (int r = 0; r < R; ++r)
        for (int m = 32; m >= 1; m >>= 1) acc[r] += __shfl_xor(acc[r], m, 64);
    if (lane == 0) {
        float bias = fcb[o];
        #pragma unroll
        for (int r = 0; r < R; ++r) ws[6160 + r * O + o] = acc[r] + bias;
    }
}

__global__ __launch_bounds__(256) void fused_main(const float* __restrict__ x,
                                                  const float* __restrict__ ws,
                                                  float* __restrict__ out) {
    __shared__ float sh_wpsi[R * C];
    __shared__ float sh_M[R * O];
    const int tid = threadIdx.x;
    const int b = blockIdx.x >> 4;          // 16 n-blocks per batch
    const int nblk = blockIdx.x & 15;
    const int n = (nblk << 8) + tid;        // pixel index in [0,4096)

    const float* wpsi_g = ws + 3072;
    const float* M_g = ws + 6160;
    for (int i = tid; i < R * C; i += 256) {
        sh_wpsi[i] = wpsi_g[i];
        sh_M[i] = M_g[i];
    }
    float swp[R], sbp[R];
    #pragma unroll
    for (int r = 0; r < R; ++r) { swp[r] = ws[6144 + r]; sbp[r] = ws[6152 + r]; }
    __syncthreads();

    const float* xb = x + (size_t)b * C * NPIX + n;
    float s = 0.f, ss = 0.f;
    float a0 = 0.f, a1 = 0.f, a2 = 0.f, a3 = 0.f, a4 = 0.f, a5 = 0.f;
    #pragma unroll 16
    for (int c = 0; c < C; ++c) {
        float xv = xb[(size_t)c * NPIX];
        s += xv;
        ss += xv * xv;
        a0 += xv * sh_wpsi[0 * C + c];
        a1 += xv * sh_wpsi[1 * C + c];
        a2 += xv * sh_wpsi[2 * C + c];
        a3 += xv * sh_wpsi[3 * C + c];
        a4 += xv * sh_wpsi[4 * C + c];
        a5 += xv * sh_wpsi[5 * C + c];
    }
    float mu = s * (1.0f / 512.0f);
    float var = ss * (1.0f / 512.0f) - mu * mu;
    float rsig = rsqrtf(var + LN_EPS);
    const float invsq = 0.04419417382415922f;  // 1/sqrt(512)

    float a[R] = {a0, a1, a2, a3, a4, a5};
    float sc[R];
    float mx = -1e30f;
    #pragma unroll
    for (int r = 0; r < R; ++r) {
        sc[r] = ((a[r] - mu * swp[r]) * rsig + sbp[r]) * invsq;
        mx = fmaxf(mx, sc[r]);
    }
    float attn[R];
    float es = 0.f;
    #pragma unroll
    for (int r = 0; r < R; ++r) { attn[r] = expf(sc[r] - mx); es += attn[r]; }
    float inv = 1.0f / es;
    #pragma unroll
    for (int r = 0; r < R; ++r) attn[r] *= inv;

    float* ob = out + (size_t)b * O * NPIX + n;
    #pragma unroll 8
    for (int o = 0; o < O; ++o) {
        float v = attn[0] * sh_M[0 * O + o] + attn[1] * sh_M[1 * O + o] +
                  attn[2] * sh_M[2 * O + o] + attn[3] * sh_M[3 * O + o] +
                  attn[4] * sh_M[4 * O + o] + attn[5] * sh_M[5 * O + o];
        ob[(size_t)o * NPIX] = v;
    }
}

extern "C" void kernel_launch(void* const* d_in, const int* in_sizes, int n_in,
                              void* d_out, int out_size, void* d_ws, size_t ws_size,
                              hipStream_t stream) {
    const float* x    = (const float*)d_in[0];
    const float* ln_w = (const float*)d_in[1];
    const float* ln_b = (const float*)d_in[2];
    const float* fc_w = (const float*)d_in[3];
    const float* fc_b = (const float*)d_in[4];
    float* out = (float*)d_out;
    float* ws = (float*)d_ws;

    setup_psi<<<1, 512, 0, stream>>>(ln_w, ln_b, ws);
    setup_M<<<O, 64, 0, stream>>>(fc_w, fc_b, ws);
    fused_main<<<BATCH * 16, 256, 0, stream>>>(x, ws, out);
}

// Round 2
// 272.267 us; speedup vs baseline: 1.0222x; 1.0222x over previous
//
#include <hip/hip_runtime.h>
#include <math.h>

#define C 512
#define NPIX 4096   // 64*64
#define BATCH 16
#define O 512
#define R 6
#define LN_EPS 1e-5f

// ws layout (floats):
// [0, 4096)      wpsiT[c*8 + r] = ln_w[c]*psi[r,c]   (r<6; pads 6,7 unused)
// [4096, 4104)   swp[r] = sum_c ln_w[c]*psi[r,c]
// [4104, 4112)   sbp[r] = sum_c ln_b[c]*psi[r,c]
// [4112, 7184)   M[r*O + o] = sum_c psi[r,c]*fc_w[o,c] + fc_b[o]
// [8192, 11264)  psi[r*C + c]   (setup_M input)

__global__ __launch_bounds__(512) void setup_psi(const float* __restrict__ lnw,
                                                 const float* __restrict__ lnb,
                                                 float* __restrict__ ws) {
    __shared__ float sh_psi[R * C];
    const int c = threadIdx.x;  // 512 threads, one per channel
    float t = -1.0f + 2.0f * (float)c / 511.0f;
    float xd = tanhf(t) * 4.31662479035539984911f;  // sqrt(11)+1
    float g = expf(-0.5f * xd * xd);
    const float pi_m14 = 0.75112554446494248286f;   // pi^-0.25
    float rows[R];
    rows[0] = pi_m14 * g;
    rows[1] = 1.41421356237309504880f * pi_m14 * xd * g;
    #pragma unroll
    for (int k = 2; k <= 5; ++k)
        rows[k] = sqrtf(2.0f / k) * xd * rows[k - 1] - sqrtf((k - 1.0f) / k) * rows[k - 2];
    float w = lnw[c];
    #pragma unroll
    for (int r = 0; r < R; ++r) {
        sh_psi[r * C + c] = rows[r];
        ws[8192 + r * C + c] = rows[r];
        ws[c * 8 + r] = rows[r] * w;
    }
    __syncthreads();
    // swp/sbp: 12 reductions over 512 channels, one per wave (2 passes of 8 waves)
    const int wv = threadIdx.x >> 6;
    const int l = threadIdx.x & 63;
    #pragma unroll
    for (int pass = 0; pass < 2; ++pass) {
        int combo = pass * 8 + wv;
        if (combo < 12) {
            int r = (combo < 6) ? combo : combo - 6;
            const float* vec = (combo < 6) ? lnw : lnb;
            float acc = 0.f;
            #pragma unroll
            for (int j = 0; j < 8; ++j) {
                int cc = l + 64 * j;
                acc += vec[cc] * sh_psi[r * C + cc];
            }
            #pragma unroll
            for (int m = 32; m >= 1; m >>= 1) acc += __shfl_xor(acc, m, 64);
            if (l == 0) ws[(combo < 6 ? 4096 : 4104) + r] = acc;
        }
    }
}

__global__ __launch_bounds__(64) void setup_M(const float* __restrict__ fcw,
                                              const float* __restrict__ fcb,
                                              float* __restrict__ ws) {
    const int o = blockIdx.x;       // 512 blocks
    const int lane = threadIdx.x;   // 64 threads = 1 wave
    const float* psi = ws + 8192;
    float acc[R] = {0.f, 0.f, 0.f, 0.f, 0.f, 0.f};
    for (int c = lane; c < C; c += 64) {
        float w = fcw[o * C + c];
        #pragma unroll
        for (int r = 0; r < R; ++r) acc[r] += psi[r * C + c] * w;
    }
    #pragma unroll
    for (int r = 0; r < R; ++r)
        for (int m = 32; m >= 1; m >>= 1) acc[r] += __shfl_xor(acc[r], m, 64);
    if (lane == 0) {
        float bias = fcb[o];
        #pragma unroll
        for (int r = 0; r < R; ++r) ws[4112 + r * O + o] = acc[r] + bias;
    }
}

// grid 1024 = 16 batches x 64 pixel-groups; block 256 = 4 waves.
// Wave w accumulates channels [w*128, w*128+128) for the block's 64 pixels
// (lane = pixel). Partials merge in LDS; lane-per-pixel softmax; then all
// 4 waves write the 64px x 512o tile with float4 stores.
__global__ __launch_bounds__(256, 4) void fused_main(const float* __restrict__ x,
                                                     const float* __restrict__ ws,
                                                     float* __restrict__ out) {
    __shared__ float shW[C * 8];        // wpsiT, 16 KB
    __shared__ float shM[R * O];        // 12 KB
    __shared__ float part[4][8][64];    // 8 KB
    __shared__ float attnS[R][64];      // 1.5 KB

    const int tid = threadIdx.x;
    const int wv = tid >> 6;
    const int l = tid & 63;
    const int b = blockIdx.x >> 6;
    const int ng = blockIdx.x & 63;
    const int n0 = ng << 6;

    // stage wpsiT + M into LDS with float4
    {
        const float4* wsrc = (const float4*)ws;
        float4* wdst = (float4*)shW;
        for (int i = tid; i < 1024; i += 256) wdst[i] = wsrc[i];
        const float4* msrc = (const float4*)(ws + 4112);
        float4* mdst = (float4*)shM;
        for (int i = tid; i < 768; i += 256) mdst[i] = msrc[i];
    }
    __syncthreads();

    // read phase: wave wv covers channels [wv*128, wv*128+128)
    const float* xb = x + ((size_t)(b * C + (wv << 7)) << 12) + n0 + l;
    float s = 0.f, ss = 0.f;
    float a0 = 0.f, a1 = 0.f, a2 = 0.f, a3 = 0.f, a4 = 0.f, a5 = 0.f;
    #pragma unroll 16
    for (int i = 0; i < 128; ++i) {
        float xv = xb[(size_t)i << 12];
        const float* wr = &shW[((wv << 7) + i) << 3];
        float4 w03 = *(const float4*)wr;
        float2 w45 = *(const float2*)(wr + 4);
        s += xv;
        ss += xv * xv;
        a0 += xv * w03.x;
        a1 += xv * w03.y;
        a2 += xv * w03.z;
        a3 += xv * w03.w;
        a4 += xv * w45.x;
        a5 += xv * w45.y;
    }
    part[wv][0][l] = s;  part[wv][1][l] = ss;
    part[wv][2][l] = a0; part[wv][3][l] = a1;
    part[wv][4][l] = a2; part[wv][5][l] = a3;
    part[wv][6][l] = a4; part[wv][7][l] = a5;
    __syncthreads();

    // combine + softmax: lane per pixel (wave 0 only)
    if (tid < 64) {
        float v[8];
        #pragma unroll
        for (int j = 0; j < 8; ++j)
            v[j] = part[0][j][tid] + part[1][j][tid] + part[2][j][tid] + part[3][j][tid];
        float mu = v[0] * (1.0f / 512.0f);
        float var = v[1] * (1.0f / 512.0f) - mu * mu;
        float rsig = rsqrtf(var + LN_EPS);
        const float invsq = 0.04419417382415922f;  // 1/sqrt(512)
        float sc[R], mx = -1e30f;
        #pragma unroll
        for (int r = 0; r < R; ++r) {
            float swp = ws[4096 + r], sbp = ws[4104 + r];
            sc[r] = ((v[2 + r] - mu * swp) * rsig + sbp) * invsq;
            mx = fmaxf(mx, sc[r]);
        }
        float es = 0.f, at[R];
        #pragma unroll
        for (int r = 0; r < R; ++r) { at[r] = expf(sc[r] - mx); es += at[r]; }
        float inv = 1.0f / es;
        #pragma unroll
        for (int r = 0; r < R; ++r) attnS[r][tid] = at[r] * inv;
    }
    __syncthreads();

    // write phase: thread covers 4 px (float4) x 32 o's
    const int pxg = (tid & 15) << 2;   // 0..60 step 4
    const int og = tid >> 4;           // 0..15
    float4 a4v[R];
    #pragma unroll
    for (int r = 0; r < R; ++r) a4v[r] = *(const float4*)&attnS[r][pxg];
    float* ob = out + ((size_t)(b * O) << 12) + n0 + pxg;
    #pragma unroll 8
    for (int k = 0; k < 32; ++k) {
        int o = og + (k << 4);
        float m0 = shM[0 * O + o], m1 = shM[1 * O + o], m2 = shM[2 * O + o];
        float m3 = shM[3 * O + o], m4 = shM[4 * O + o], m5 = shM[5 * O + o];
        float4 res;
        res.x = a4v[0].x * m0 + a4v[1].x * m1 + a4v[2].x * m2 + a4v[3].x * m3 + a4v[4].x * m4 + a4v[5].x * m5;
        res.y = a4v[0].y * m0 + a4v[1].y * m1 + a4v[2].y * m2 + a4v[3].y * m3 + a4v[4].y * m4 + a4v[5].y * m5;
        res.z = a4v[0].z * m0 + a4v[1].z * m1 + a4v[2].z * m2 + a4v[3].z * m3 + a4v[4].z * m4 + a4v[5].z * m5;
        res.w = a4v[0].w * m0 + a4v[1].w * m1 + a4v[2].w * m2 + a4v[3].w * m3 + a4v[4].w * m4 + a4v[5].w * m5;
        *(float4*)(ob + ((size_t)o << 12)) = res;
    }
}

extern "C" void kernel_launch(void* const* d_in, const int* in_sizes, int n_in,
                              void* d_out, int out_size, void* d_ws, size_t ws_size,
                              hipStream_t stream) {
    const float* x    = (const float*)d_in[0];
    const float* ln_w = (const float*)d_in[1];
    const float* ln_b = (const float*)d_in[2];
    const float* fc_w = (const float*)d_in[3];
    const float* fc_b = (const float*)d_in[4];
    float* out = (float*)d_out;
    float* ws = (float*)d_ws;

    setup_psi<<<1, 512, 0, stream>>>(ln_w, ln_b, ws);
    setup_M<<<O, 64, 0, stream>>>(fc_w, fc_b, ws);
    fused_main<<<BATCH * 64, 256, 0, stream>>>(x, ws, out);
}

// Round 4
// 245.366 us; speedup vs baseline: 1.1342x; 1.1096x over previous
//
#include <hip/hip_runtime.h>
#include <math.h>

#define C 512
#define NPIX 4096   // 64*64
#define BATCH 16
#define O 512
#define R 6
#define LN_EPS 1e-5f
#define ATTN_OFF 16384   // float offset of attn[b][r][n] in ws (16*6*4096 floats)

typedef float vf4 __attribute__((ext_vector_type(4)));

// ws layout (floats):
// [0, 4096)      wpsiT[c*8 + r] = ln_w[c]*psi[r,c]   (r<6; pads 6,7 unused)
// [4096, 4104)   swp[r] = sum_c ln_w[c]*psi[r,c]
// [4104, 4112)   sbp[r] = sum_c ln_b[c]*psi[r,c]
// [4112, 7184)   M[r*O + o] = sum_c psi[r,c]*fc_w[o,c] + fc_b[o]
// [8192, 11264)  psi[r*C + c]   (setup_M input)
// [16384, 409600) attn[b*6*4096 + r*4096 + n]

__global__ __launch_bounds__(512) void setup_psi(const float* __restrict__ lnw,
                                                 const float* __restrict__ lnb,
                                                 float* __restrict__ ws) {
    __shared__ float sh_psi[R * C];
    const int c = threadIdx.x;  // 512 threads, one per channel
    float t = -1.0f + 2.0f * (float)c / 511.0f;
    float xd = tanhf(t) * 4.31662479035539984911f;  // sqrt(11)+1
    float g = expf(-0.5f * xd * xd);
    const float pi_m14 = 0.75112554446494248286f;   // pi^-0.25
    float rows[R];
    rows[0] = pi_m14 * g;
    rows[1] = 1.41421356237309504880f * pi_m14 * xd * g;
    #pragma unroll
    for (int k = 2; k <= 5; ++k)
        rows[k] = sqrtf(2.0f / k) * xd * rows[k - 1] - sqrtf((k - 1.0f) / k) * rows[k - 2];
    float w = lnw[c];
    #pragma unroll
    for (int r = 0; r < R; ++r) {
        sh_psi[r * C + c] = rows[r];
        ws[8192 + r * C + c] = rows[r];
        ws[c * 8 + r] = rows[r] * w;
    }
    __syncthreads();
    const int wv = threadIdx.x >> 6;
    const int l = threadIdx.x & 63;
    #pragma unroll
    for (int pass = 0; pass < 2; ++pass) {
        int combo = pass * 8 + wv;
        if (combo < 12) {
            int r = (combo < 6) ? combo : combo - 6;
            const float* vec = (combo < 6) ? lnw : lnb;
            float acc = 0.f;
            #pragma unroll
            for (int j = 0; j < 8; ++j) {
                int cc = l + 64 * j;
                acc += vec[cc] * sh_psi[r * C + cc];
            }
            #pragma unroll
            for (int m = 32; m >= 1; m >>= 1) acc += __shfl_xor(acc, m, 64);
            if (l == 0) ws[(combo < 6 ? 4096 : 4104) + r] = acc;
        }
    }
}

__global__ __launch_bounds__(64) void setup_M(const float* __restrict__ fcw,
                                              const float* __restrict__ fcb,
                                              float* __restrict__ ws) {
    const int o = blockIdx.x;       // 512 blocks
    const int lane = threadIdx.x;   // 64 threads = 1 wave
    const float* psi = ws + 8192;
    float acc[R] = {0.f, 0.f, 0.f, 0.f, 0.f, 0.f};
    for (int c = lane; c < C; c += 64) {
        float w = fcw[o * C + c];
        #pragma unroll
        for (int r = 0; r < R; ++r) acc[r] += psi[r * C + c] * w;
    }
    #pragma unroll
    for (int r = 0; r < R; ++r)
        for (int m = 32; m >= 1; m >>= 1) acc[r] += __shfl_xor(acc[r], m, 64);
    if (lane == 0) {
        float bias = fcb[o];
        #pragma unroll
        for (int r = 0; r < R; ++r) ws[4112 + r * O + o] = acc[r] + bias;
    }
}

// Phase A: pure read stream. 256 blocks (16 b x 16 px-groups) x 512 threads.
// Wave wv covers channels [wv*64, wv*64+64) for the block's 256 pixels;
// lane l owns pixels 4l..4l+3 via float4 loads (16 B/lane, 1 KB/instr).
// Stats accumulate in registers; one LDS combine; softmax; attn -> ws.
__global__ __launch_bounds__(512) void stats_kernel(const float* __restrict__ x,
                                                    const float* __restrict__ ws,
                                                    float* __restrict__ attn) {
    __shared__ float part[8][8][256];   // [wave][stat][px], 64 KB
    const int tid = threadIdx.x;
    const int wv = tid >> 6;
    const int l = tid & 63;
    const int b = blockIdx.x >> 4;
    const int pxg = blockIdx.x & 15;
    const int n0 = pxg << 8;
    const int wuni = __builtin_amdgcn_readfirstlane(wv);  // force SGPR

    const float* xb = x + (((size_t)(b * C + (wuni << 6))) << 12) + n0 + (l << 2);
    const float* wbase = ws + ((size_t)(wuni << 6) << 3);

    float4 s = {0.f,0.f,0.f,0.f}, ss = s;
    float4 a0 = s, a1 = s, a2 = s, a3 = s, a4 = s, a5 = s;
    #pragma unroll 8
    for (int i = 0; i < 64; ++i) {
        float4 xv = *(const float4*)(xb + ((size_t)i << 12));
        const float* wr = wbase + (i << 3);     // wave-uniform -> s_load
        float w0 = wr[0], w1 = wr[1], w2 = wr[2];
        float w3 = wr[3], w4 = wr[4], w5 = wr[5];
        s.x += xv.x;  s.y += xv.y;  s.z += xv.z;  s.w += xv.w;
        ss.x += xv.x * xv.x; ss.y += xv.y * xv.y; ss.z += xv.z * xv.z; ss.w += xv.w * xv.w;
        a0.x += xv.x * w0; a0.y += xv.y * w0; a0.z += xv.z * w0; a0.w += xv.w * w0;
        a1.x += xv.x * w1; a1.y += xv.y * w1; a1.z += xv.z * w1; a1.w += xv.w * w1;
        a2.x += xv.x * w2; a2.y += xv.y * w2; a2.z += xv.z * w2; a2.w += xv.w * w2;
        a3.x += xv.x * w3; a3.y += xv.y * w3; a3.z += xv.z * w3; a3.w += xv.w * w3;
        a4.x += xv.x * w4; a4.y += xv.y * w4; a4.z += xv.z * w4; a4.w += xv.w * w4;
        a5.x += xv.x * w5; a5.y += xv.y * w5; a5.z += xv.z * w5; a5.w += xv.w * w5;
    }
    *(float4*)&part[wv][0][l << 2] = s;
    *(float4*)&part[wv][1][l << 2] = ss;
    *(float4*)&part[wv][2][l << 2] = a0;
    *(float4*)&part[wv][3][l << 2] = a1;
    *(float4*)&part[wv][4][l << 2] = a2;
    *(float4*)&part[wv][5][l << 2] = a3;
    *(float4*)&part[wv][6][l << 2] = a4;
    *(float4*)&part[wv][7][l << 2] = a5;
    __syncthreads();

    if (tid < 256) {
        float v[8];
        #pragma unroll
        for (int st = 0; st < 8; ++st) {
            float acc = 0.f;
            #pragma unroll
            for (int w = 0; w < 8; ++w) acc += part[w][st][tid];
            v[st] = acc;
        }
        float mu = v[0] * (1.0f / 512.0f);
        float var = v[1] * (1.0f / 512.0f) - mu * mu;
        float rsig = rsqrtf(var + LN_EPS);
        const float invsq = 0.04419417382415922f;  // 1/sqrt(512)
        float sc[R], mx = -1e30f;
        #pragma unroll
        for (int r = 0; r < R; ++r) {
            float swp = ws[4096 + r], sbp = ws[4104 + r];
            sc[r] = ((v[2 + r] - mu * swp) * rsig + sbp) * invsq;
            mx = fmaxf(mx, sc[r]);
        }
        float es = 0.f, at[R];
        #pragma unroll
        for (int r = 0; r < R; ++r) { at[r] = expf(sc[r] - mx); es += at[r]; }
        float inv = 1.0f / es;
        #pragma unroll
        for (int r = 0; r < R; ++r)
            attn[(((size_t)(b * 6 + r)) << 12) + n0 + tid] = at[r] * inv;
    }
}

// Phase B: pure write stream. 4096 blocks (16 b x 4 px-groups(1024) x 64 o-groups(8))
// x 256 threads. Thread owns 4 px (float4) x 8 o-rows; attn read once per thread
// (L2-served), M via wave-uniform scalar loads; nontemporal float4 stores.
__global__ __launch_bounds__(256) void bcast_kernel(const float* __restrict__ ws,
                                                    float* __restrict__ out) {
    const int tid = threadIdx.x;
    const int bid = blockIdx.x;
    const int b = bid >> 8;
    const int pxg = (bid >> 6) & 3;
    const int og = bid & 63;
    const int n = (pxg << 10) + (tid << 2);

    const float* attn = ws + ATTN_OFF;
    float4 ar[R];
    #pragma unroll
    for (int r = 0; r < R; ++r)
        ar[r] = *(const float4*)(attn + (((size_t)(b * 6 + r)) << 12) + n);

    float* ob = out + (((size_t)(b * O + (og << 3))) << 12) + n;
    #pragma unroll
    for (int j = 0; j < 8; ++j) {
        int o = (og << 3) + j;  // uniform -> M loads scalarize
        float m0 = ws[4112 + 0 * O + o];
        float m1 = ws[4112 + 1 * O + o];
        float m2 = ws[4112 + 2 * O + o];
        float m3 = ws[4112 + 3 * O + o];
        float m4 = ws[4112 + 4 * O + o];
        float m5 = ws[4112 + 5 * O + o];
        vf4 res;
        res.x = ar[0].x * m0 + ar[1].x * m1 + ar[2].x * m2 + ar[3].x * m3 + ar[4].x * m4 + ar[5].x * m5;
        res.y = ar[0].y * m0 + ar[1].y * m1 + ar[2].y * m2 + ar[3].y * m3 + ar[4].y * m4 + ar[5].y * m5;
        res.z = ar[0].z * m0 + ar[1].z * m1 + ar[2].z * m2 + ar[3].z * m3 + ar[4].z * m4 + ar[5].z * m5;
        res.w = ar[0].w * m0 + ar[1].w * m1 + ar[2].w * m2 + ar[3].w * m3 + ar[4].w * m4 + ar[5].w * m5;
        __builtin_nontemporal_store(res, (vf4*)(ob + ((size_t)j << 12)));
    }
}

extern "C" void kernel_launch(void* const* d_in, const int* in_sizes, int n_in,
                              void* d_out, int out_size, void* d_ws, size_t ws_size,
                              hipStream_t stream) {
    const float* x    = (const float*)d_in[0];
    const float* ln_w = (const float*)d_in[1];
    const float* ln_b = (const float*)d_in[2];
    const float* fc_w = (const float*)d_in[3];
    const float* fc_b = (const float*)d_in[4];
    float* out = (float*)d_out;
    float* ws = (float*)d_ws;

    setup_psi<<<1, 512, 0, stream>>>(ln_w, ln_b, ws);
    setup_M<<<O, 64, 0, stream>>>(fc_w, fc_b, ws);
    stats_kernel<<<BATCH * 16, 512, 0, stream>>>(x, ws, ws + ATTN_OFF);
    bcast_kernel<<<4096, 256, 0, stream>>>(ws, out);
}